// Round 2
// baseline (1027.308 us; speedup 1.0000x reference)
//
#include <hip/hip_runtime.h>
#include <math.h>

// Problem constants (N = 1024)
#define M_ROWS  81920            // 1024*8*10 score rows
#define NCOLS   4096
#define KPAD    48               // 45 padded to 48 (3 k-tiles of 16 for 32x32x16)
#define NCHUNK  8
#define CHUNKC  (NCOLS / NCHUNK) // 512 cols per chunk (one wave each)
#define CROUNDS (CHUNKC / 32)    // 16 col-rounds of 32 cols
#define LO_SCALE 4096.0f         // 2^12: keeps f16 residuals out of subnormal range
#define INV_LO   (1.0f / 4096.0f)

typedef _Float16 f16x8  __attribute__((ext_vector_type(8)));
typedef float    f32x16 __attribute__((ext_vector_type(16)));

// ws layout (~0.79 MB):
//   Bhi  : _Float16[4096 * 48]   ([col][k], pad zeroed)   0.39 MB
//   Blo  : _Float16[4096 * 48]   (residual * 2^12)        0.39 MB
// All prefetches are clamped in-range: no overread past Blo.

// ---------------------------------------------------------------------------
// Build B: split H (45 x 4096, [d][n]) into hi/lo f16 in [col][k] layout,
// 48 k's per col (96 B stride, 16B-aligned), pad k=45..47 zeroed.
__global__ void build_B_kernel(const float* __restrict__ H,
                               _Float16* __restrict__ Bhi,
                               _Float16* __restrict__ Blo) {
    const int n = blockIdx.x * 256 + threadIdx.x;
    _Float16 hi[KPAD], lo[KPAD];
    #pragma unroll
    for (int k = 0; k < 45; ++k) {
        const float h = H[k * NCOLS + n];
        const _Float16 h1 = (_Float16)h;
        hi[k] = h1;
        lo[k] = (_Float16)((h - (float)h1) * LO_SCALE);
    }
    #pragma unroll
    for (int k = 45; k < KPAD; ++k) { hi[k] = (_Float16)0.f; lo[k] = (_Float16)0.f; }
    f16x8* dh = (f16x8*)(Bhi + (size_t)n * KPAD);
    f16x8* dl = (f16x8*)(Blo + (size_t)n * KPAD);
    const f16x8* sh = (const f16x8*)hi;
    const f16x8* sl = (const f16x8*)lo;
    #pragma unroll
    for (int q = 0; q < KPAD / 8; ++q) { dh[q] = sh[q]; dl[q] = sl[q]; }
}

// ---------------------------------------------------------------------------
// Fused MFMA GEMM + argmax + chunk-reduce + LUT gather.
// Block = 512 threads = 8 waves; wave w handles chunk w (512 cols) for the
// block's 64-row group. Per-wave argmax -> LDS -> block reduce -> LUT write.
// 32x32 layouts: A[m=lane&31][k=(lane>>5)*8+j]; B[k=(lane>>5)*8+j][n=lane&31];
// C/D: col=lane&31, row=(reg&3)+8*(reg>>2)+4*(lane>>5)   (m74/m101-verified).
__global__ __launch_bounds__(512, 4) void score_argmax_kernel(
        const float* __restrict__ x,   // (1024, 480)
        const float* __restrict__ S,   // (30, 2, 15)
        const float* __restrict__ T,   // (30, 15)
        const _Float16* __restrict__ Bhi,
        const _Float16* __restrict__ Blo,
        const float* __restrict__ LUT, // (10, 4096, 2)
        float* __restrict__ out) {     // (81920, 2)
    const int tid  = threadIdx.x;
    const int lane = tid & 63;
    const int l31  = lane & 31;
    const int half = lane >> 5;                       // 0 or 1
    const int chunk = tid >> 6;                       // wave id == chunk [0,8)
    const int rg    = blockIdx.x;                     // row-group [0,1280)
    const int rowbase = rg * 64;

    __shared__ float lds_best[NCHUNK][64];
    __shared__ int   lds_bidx[NCHUNK][64];

    // ---- inline A: afr[rt][kt][j] = y(rowbase + rt*32 + l31, kt*16 + half*8 + j)
    // y = sign(x4·S - T - 1e-4), exactly ±1/0 in f16; zero for k >= 45.
    // (identical for all 8 waves of the block; duplicated compute, no sync)
    f16x8 afr[2][3];
    #pragma unroll
    for (int rt = 0; rt < 2; ++rt) {
        const int row  = rowbase + rt * 32 + l31;
        const int pair = row / 10;
        const int c2   = row - pair * 10;
        const int a    = pair >> 3;
        const int b    = pair & 7;
        const float* xp = x + a * 480 + b * 60;
        #pragma unroll
        for (int kt = 0; kt < 3; ++kt) {
            #pragma unroll
            for (int j = 0; j < 8; ++j) {
                const int k    = kt * 16 + half * 8 + j;     // [0,48)
                const bool pad = (k >= 45);
                const int kcl  = pad ? 0 : k;                // clamp for safe addrs
                const int cc   = kcl / 15;                   // const-divisor magic
                const int kk   = kcl - cc * 15;
                const int c    = c2 * 3 + cc;
                const float x0 = xp[c * 2 + 0];
                const float x1 = xp[c * 2 + 1];
                float v = x0 * S[(c * 2 + 0) * 15 + kk] + x1 * S[(c * 2 + 1) * 15 + kk];
                v = v - T[c * 15 + kk] - 1e-4f;
                const float yv = (v > 0.f) ? 1.f : ((v < 0.f) ? -1.f : 0.f);
                afr[rt][kt][j] = pad ? (_Float16)0.f : (_Float16)yv;
            }
        }
    }

    float best[2][16];
    int   bidx[2][16];
    #pragma unroll
    for (int rt = 0; rt < 2; ++rt)
        #pragma unroll
        for (int e = 0; e < 16; ++e) { best[rt][e] = -INFINITY; bidx[rt][e] = 0; }

    const int colbase0 = chunk * CHUNKC;
    // per-lane B base: col = colbase0 + l31, byte = col*96 + half*16 (+kt*32)
    const _Float16* hbase = Bhi + (size_t)(colbase0 + l31) * KPAD + half * 8;
    const _Float16* lbase = Blo + (size_t)(colbase0 + l31) * KPAD + half * 8;
    const size_t RS = (size_t)32 * KPAD;              // halves per 32-col round

#define PREFETCH(dst, rr) do {                                              \
        const _Float16* hp_ = hbase + (size_t)(rr) * RS;                    \
        const _Float16* lp_ = lbase + (size_t)(rr) * RS;                    \
        _Pragma("unroll")                                                   \
        for (int kt_ = 0; kt_ < 3; ++kt_) {                                 \
            (dst)[kt_]     = *(const f16x8*)(hp_ + kt_ * 16);               \
            (dst)[3 + kt_] = *(const f16x8*)(lp_ + kt_ * 16);               \
        } } while (0)

#define COMPUTE(buf, ct) do {                                               \
        const int mycol_ = colbase0 + (ct) * 32 + l31;                      \
        _Pragma("unroll")                                                   \
        for (int rt_ = 0; rt_ < 2; ++rt_) {                                 \
            f32x16 ch = {0.f};                                              \
            f32x16 cl = {0.f};                                              \
            ch = __builtin_amdgcn_mfma_f32_32x32x16_f16(afr[rt_][0], (buf)[0], ch, 0, 0, 0); \
            ch = __builtin_amdgcn_mfma_f32_32x32x16_f16(afr[rt_][1], (buf)[1], ch, 0, 0, 0); \
            ch = __builtin_amdgcn_mfma_f32_32x32x16_f16(afr[rt_][2], (buf)[2], ch, 0, 0, 0); \
            cl = __builtin_amdgcn_mfma_f32_32x32x16_f16(afr[rt_][0], (buf)[3], cl, 0, 0, 0); \
            cl = __builtin_amdgcn_mfma_f32_32x32x16_f16(afr[rt_][1], (buf)[4], cl, 0, 0, 0); \
            cl = __builtin_amdgcn_mfma_f32_32x32x16_f16(afr[rt_][2], (buf)[5], cl, 0, 0, 0); \
            _Pragma("unroll")                                               \
            for (int e_ = 0; e_ < 16; ++e_) {                               \
                const float s_ = fmaf(cl[e_], INV_LO, ch[e_]);              \
                if (s_ > best[rt_][e_]) bidx[rt_][e_] = mycol_;             \
                best[rt_][e_] = fmaxf(best[rt_][e_], s_);                   \
            }                                                               \
        } } while (0)

    // double-buffered B fragments (hi/lo x 3 k-tiles), ping-pong unrolled x2
    // so no per-round register copies. CROUNDS = 16 (even).
    f16x8 cb[6], nb[6];
    PREFETCH(cb, 0);
    for (int it = 0; it < CROUNDS; it += 2) {
        PREFETCH(nb, it + 1);                 // it+1 <= 15: always in range
        COMPUTE(cb, it);
        const int pf2 = (it + 2 < CROUNDS) ? (it + 2) : 0;  // clamp: no overread
        PREFETCH(cb, pf2);
        COMPUTE(nb, it + 1);
    }
#undef PREFETCH
#undef COMPUTE

    // Cross-lane argmax over the 32 cols held by l31=0..31 (same half).
    // Tie -> smaller index (jnp.argmax first-index semantics).
    #pragma unroll
    for (int m = 1; m < 32; m <<= 1) {
        #pragma unroll
        for (int rt = 0; rt < 2; ++rt)
            #pragma unroll
            for (int e = 0; e < 16; ++e) {
                const float ov = __shfl_xor(best[rt][e], m, 64);
                const int   oi = __shfl_xor(bidx[rt][e], m, 64);
                if (ov > best[rt][e] ||
                    (ov == best[rt][e] && oi < bidx[rt][e])) {
                    best[rt][e] = ov; bidx[rt][e] = oi;
                }
            }
    }

    if (l31 == 0) {   // lanes 0 and 32 write their half's rows
        #pragma unroll
        for (int rt = 0; rt < 2; ++rt)
            #pragma unroll
            for (int e = 0; e < 16; ++e) {
                const int r64 = rt * 32 + (e & 3) + 8 * (e >> 2) + 4 * half;
                lds_best[chunk][r64] = best[rt][e];
                lds_bidx[chunk][r64] = bidx[rt][e];
            }
    }
    __syncthreads();

    // Fold the 8 chunk partials (ascending chunk + strict > == global
    // first-index argmax), gather LUT, write out (row-major (1024,8,10,2)).
    if (tid < 64) {
        const int row = rowbase + tid;
        float bv = lds_best[0][tid];
        int   bi = lds_bidx[0][tid];
        #pragma unroll
        for (int c = 1; c < NCHUNK; ++c) {
            const float v = lds_best[c][tid];
            const int   i = lds_bidx[c][tid];
            if (v > bv) { bv = v; bi = i; }
        }
        const int pair = row / 10;
        const int c2   = row - pair * 10;
        const float* l = LUT + ((size_t)c2 * NCOLS + bi) * 2;
        out[row * 2 + 0] = l[0];
        out[row * 2 + 1] = l[1];
    }
}

// ---------------------------------------------------------------------------
extern "C" void kernel_launch(void* const* d_in, const int* in_sizes, int n_in,
                              void* d_out, int out_size, void* d_ws, size_t ws_size,
                              hipStream_t stream) {
    const float* x   = (const float*)d_in[0];  // 1024*480
    const float* S   = (const float*)d_in[1];  // 30*2*15
    const float* T   = (const float*)d_in[2];  // 30*15
    const float* H   = (const float*)d_in[3];  // 45*4096
    const float* LUT = (const float*)d_in[4];  // 10*4096*2
    float* out = (float*)d_out;                // 1024*8*10*2

    _Float16* Bhi = (_Float16*)d_ws;                          // 4096*48
    _Float16* Blo = Bhi + (size_t)NCOLS * KPAD;               // 4096*48

    build_B_kernel<<<16, 256, 0, stream>>>(H, Bhi, Blo);
    // 1280 blocks x 8 waves: each block = one 64-row group x all 8 chunks.
    // 10240 waves total = 2.5 fills at 4 waves/SIMD.
    score_argmax_kernel<<<1280, 512, 0, stream>>>(x, S, T, Bhi, Blo, LUT, out);
}

// Round 3
// 298.087 us; speedup vs baseline: 3.4463x; 3.4463x over previous
//
#include <hip/hip_runtime.h>
#include <math.h>

// Problem constants (N = 1024)
#define M_ROWS  81920            // 1024*8*10 score rows
#define NCOLS   4096
#define KPAD    48               // 45 padded to 48 (3 k-tiles of 16 for 32x32x16)
#define NCHUNK  8
#define CHUNKC  (NCOLS / NCHUNK) // 512 cols per chunk (one wave each)
#define CROUNDS (CHUNKC / 32)    // 16 col-rounds of 32 cols
#define LO_SCALE 4096.0f         // 2^12: keeps f16 residuals out of subnormal range
#define INV_LO   (1.0f / 4096.0f)

typedef _Float16 f16x8  __attribute__((ext_vector_type(8)));
typedef float    f32x16 __attribute__((ext_vector_type(16)));

// ws layout (~0.79 MB):
//   Bhi  : _Float16[4096 * 48]   ([col][k], pad zeroed)   0.39 MB
//   Blo  : _Float16[4096 * 48]   (residual * 2^12)        0.39 MB
// All prefetches are clamped in-range: no overread past Blo.

// ---------------------------------------------------------------------------
// Build B: split H (45 x 4096, [d][n]) into hi/lo f16 in [col][k] layout,
// 48 k's per col (96 B stride, 16B-aligned), pad k=45..47 zeroed.
__global__ void build_B_kernel(const float* __restrict__ H,
                               _Float16* __restrict__ Bhi,
                               _Float16* __restrict__ Blo) {
    const int n = blockIdx.x * 256 + threadIdx.x;
    _Float16 hi[KPAD], lo[KPAD];
    #pragma unroll
    for (int k = 0; k < 45; ++k) {
        const float h = H[k * NCOLS + n];
        const _Float16 h1 = (_Float16)h;
        hi[k] = h1;
        lo[k] = (_Float16)((h - (float)h1) * LO_SCALE);
    }
    #pragma unroll
    for (int k = 45; k < KPAD; ++k) { hi[k] = (_Float16)0.f; lo[k] = (_Float16)0.f; }
    f16x8* dh = (f16x8*)(Bhi + (size_t)n * KPAD);
    f16x8* dl = (f16x8*)(Blo + (size_t)n * KPAD);
    const f16x8* sh = (const f16x8*)hi;
    const f16x8* sl = (const f16x8*)lo;
    #pragma unroll
    for (int q = 0; q < KPAD / 8; ++q) { dh[q] = sh[q]; dl[q] = sl[q]; }
}

// ---------------------------------------------------------------------------
// Fused MFMA GEMM + argmax + chunk-reduce + LUT gather.
// Block = 512 threads = 8 waves; wave w handles chunk w (512 cols) for the
// block's 64-row group. Per-wave argmax -> LDS -> block reduce -> LUT write.
//
// LAUNCH BOUNDS NOTE (measured round 2): (512,4) forced a 64-VGPR cap ->
// catastrophic scratch spill (4.3 GB HBM traffic/dispatch, 1011 us).
// (512,2) leaves a >=128-VGPR budget; kernel fits (~112) -> 4 waves/SIMD.
//
// 32x32 layouts: A[m=lane&31][k=(lane>>5)*8+j]; B[k=(lane>>5)*8+j][n=lane&31];
// C/D: col=lane&31, row=(reg&3)+8*(reg>>2)+4*(lane>>5)   (m74/m101-verified).
__global__ __launch_bounds__(512, 2) void score_argmax_kernel(
        const float* __restrict__ x,   // (1024, 480)
        const float* __restrict__ S,   // (30, 2, 15)
        const float* __restrict__ T,   // (30, 15)
        const _Float16* __restrict__ Bhi,
        const _Float16* __restrict__ Blo,
        const float* __restrict__ LUT, // (10, 4096, 2)
        float* __restrict__ out) {     // (81920, 2)
    const int tid  = threadIdx.x;
    const int lane = tid & 63;
    const int l31  = lane & 31;
    const int half = lane >> 5;                       // 0 or 1
    const int chunk = tid >> 6;                       // wave id == chunk [0,8)
    const int rg    = blockIdx.x;                     // row-group [0,1280)
    const int rowbase = rg * 64;

    __shared__ float lds_best[NCHUNK][64];
    __shared__ int   lds_bidx[NCHUNK][64];

    // ---- inline A: afr[rt][kt][j] = y(rowbase + rt*32 + l31, kt*16 + half*8 + j)
    // y = sign(x4·S - T - 1e-4), exactly ±1/0 in f16; zero for k >= 45.
    // (identical for all 8 waves of the block; duplicated compute, no sync)
    f16x8 afr[2][3];
    #pragma unroll
    for (int rt = 0; rt < 2; ++rt) {
        const int row  = rowbase + rt * 32 + l31;
        const int pair = row / 10;
        const int c2   = row - pair * 10;
        const int a    = pair >> 3;
        const int b    = pair & 7;
        const float* xp = x + a * 480 + b * 60;
        #pragma unroll
        for (int kt = 0; kt < 3; ++kt) {
            #pragma unroll
            for (int j = 0; j < 8; ++j) {
                const int k    = kt * 16 + half * 8 + j;     // [0,48)
                const bool pad = (k >= 45);
                const int kcl  = pad ? 0 : k;                // clamp for safe addrs
                const int cc   = kcl / 15;                   // const-divisor magic
                const int kk   = kcl - cc * 15;
                const int c    = c2 * 3 + cc;
                const float x0 = xp[c * 2 + 0];
                const float x1 = xp[c * 2 + 1];
                float v = x0 * S[(c * 2 + 0) * 15 + kk] + x1 * S[(c * 2 + 1) * 15 + kk];
                v = v - T[c * 15 + kk] - 1e-4f;
                const float yv = (v > 0.f) ? 1.f : ((v < 0.f) ? -1.f : 0.f);
                afr[rt][kt][j] = pad ? (_Float16)0.f : (_Float16)yv;
            }
        }
    }

    float best[2][16];
    int   bidx[2][16];
    #pragma unroll
    for (int rt = 0; rt < 2; ++rt)
        #pragma unroll
        for (int e = 0; e < 16; ++e) { best[rt][e] = -INFINITY; bidx[rt][e] = 0; }

    const int colbase0 = chunk * CHUNKC;
    // per-lane B base: col = colbase0 + l31, byte = col*96 + half*16 (+kt*32)
    const _Float16* hbase = Bhi + (size_t)(colbase0 + l31) * KPAD + half * 8;
    const _Float16* lbase = Blo + (size_t)(colbase0 + l31) * KPAD + half * 8;
    const size_t RS = (size_t)32 * KPAD;              // halves per 32-col round

#define PREFETCH(dst, rr) do {                                              \
        const _Float16* hp_ = hbase + (size_t)(rr) * RS;                    \
        const _Float16* lp_ = lbase + (size_t)(rr) * RS;                    \
        _Pragma("unroll")                                                   \
        for (int kt_ = 0; kt_ < 3; ++kt_) {                                 \
            (dst)[kt_]     = *(const f16x8*)(hp_ + kt_ * 16);               \
            (dst)[3 + kt_] = *(const f16x8*)(lp_ + kt_ * 16);               \
        } } while (0)

#define COMPUTE(buf, ct) do {                                               \
        const int mycol_ = colbase0 + (ct) * 32 + l31;                      \
        _Pragma("unroll")                                                   \
        for (int rt_ = 0; rt_ < 2; ++rt_) {                                 \
            f32x16 ch = {0.f};                                              \
            f32x16 cl = {0.f};                                              \
            ch = __builtin_amdgcn_mfma_f32_32x32x16_f16(afr[rt_][0], (buf)[0], ch, 0, 0, 0); \
            ch = __builtin_amdgcn_mfma_f32_32x32x16_f16(afr[rt_][1], (buf)[1], ch, 0, 0, 0); \
            ch = __builtin_amdgcn_mfma_f32_32x32x16_f16(afr[rt_][2], (buf)[2], ch, 0, 0, 0); \
            cl = __builtin_amdgcn_mfma_f32_32x32x16_f16(afr[rt_][0], (buf)[3], cl, 0, 0, 0); \
            cl = __builtin_amdgcn_mfma_f32_32x32x16_f16(afr[rt_][1], (buf)[4], cl, 0, 0, 0); \
            cl = __builtin_amdgcn_mfma_f32_32x32x16_f16(afr[rt_][2], (buf)[5], cl, 0, 0, 0); \
            _Pragma("unroll")                                               \
            for (int e_ = 0; e_ < 16; ++e_) {                               \
                const float s_ = fmaf(cl[e_], INV_LO, ch[e_]);              \
                if (s_ > best[rt_][e_]) bidx[rt_][e_] = mycol_;             \
                best[rt_][e_] = fmaxf(best[rt_][e_], s_);                   \
            }                                                               \
        } } while (0)

    // double-buffered B fragments (hi/lo x 3 k-tiles), ping-pong unrolled x2
    // so no per-round register copies. CROUNDS = 16 (even).
    f16x8 cb[6], nb[6];
    PREFETCH(cb, 0);
    for (int it = 0; it < CROUNDS; it += 2) {
        PREFETCH(nb, it + 1);                 // it+1 <= 15: always in range
        COMPUTE(cb, it);
        const int pf2 = (it + 2 < CROUNDS) ? (it + 2) : 0;  // clamp: no overread
        PREFETCH(cb, pf2);
        COMPUTE(nb, it + 1);
    }
#undef PREFETCH
#undef COMPUTE

    // Cross-lane argmax over the 32 cols held by l31=0..31 (same half).
    // Tie -> smaller index (jnp.argmax first-index semantics).
    #pragma unroll
    for (int m = 1; m < 32; m <<= 1) {
        #pragma unroll
        for (int rt = 0; rt < 2; ++rt)
            #pragma unroll
            for (int e = 0; e < 16; ++e) {
                const float ov = __shfl_xor(best[rt][e], m, 64);
                const int   oi = __shfl_xor(bidx[rt][e], m, 64);
                if (ov > best[rt][e] ||
                    (ov == best[rt][e] && oi < bidx[rt][e])) {
                    best[rt][e] = ov; bidx[rt][e] = oi;
                }
            }
    }

    if (l31 == 0) {   // lanes 0 and 32 write their half's rows
        #pragma unroll
        for (int rt = 0; rt < 2; ++rt)
            #pragma unroll
            for (int e = 0; e < 16; ++e) {
                const int r64 = rt * 32 + (e & 3) + 8 * (e >> 2) + 4 * half;
                lds_best[chunk][r64] = best[rt][e];
                lds_bidx[chunk][r64] = bidx[rt][e];
            }
    }
    __syncthreads();

    // Fold the 8 chunk partials (ascending chunk + strict > == global
    // first-index argmax), gather LUT, write out (row-major (1024,8,10,2)).
    if (tid < 64) {
        const int row = rowbase + tid;
        float bv = lds_best[0][tid];
        int   bi = lds_bidx[0][tid];
        #pragma unroll
        for (int c = 1; c < NCHUNK; ++c) {
            const float v = lds_best[c][tid];
            const int   i = lds_bidx[c][tid];
            if (v > bv) { bv = v; bi = i; }
        }
        const int pair = row / 10;
        const int c2   = row - pair * 10;
        const float* l = LUT + ((size_t)c2 * NCOLS + bi) * 2;
        out[row * 2 + 0] = l[0];
        out[row * 2 + 1] = l[1];
    }
}

// ---------------------------------------------------------------------------
extern "C" void kernel_launch(void* const* d_in, const int* in_sizes, int n_in,
                              void* d_out, int out_size, void* d_ws, size_t ws_size,
                              hipStream_t stream) {
    const float* x   = (const float*)d_in[0];  // 1024*480
    const float* S   = (const float*)d_in[1];  // 30*2*15
    const float* T   = (const float*)d_in[2];  // 30*15
    const float* H   = (const float*)d_in[3];  // 45*4096
    const float* LUT = (const float*)d_in[4];  // 10*4096*2
    float* out = (float*)d_out;                // 1024*8*10*2

    _Float16* Bhi = (_Float16*)d_ws;                          // 4096*48
    _Float16* Blo = Bhi + (size_t)NCOLS * KPAD;               // 4096*48

    build_B_kernel<<<16, 256, 0, stream>>>(H, Bhi, Blo);
    // 1280 blocks x 8 waves: each block = one 64-row group x all 8 chunks.
    // 10240 waves total; ~112 VGPR -> 4 waves/SIMD resident (2 blocks/CU).
    score_argmax_kernel<<<1280, 512, 0, stream>>>(x, S, T, Bhi, Blo, LUT, out);
}

// Round 4
// 234.918 us; speedup vs baseline: 4.3730x; 1.2689x over previous
//
#include <hip/hip_runtime.h>
#include <math.h>

// Problem constants (N = 1024)
#define M_ROWS  81920            // 1024*8*10 score rows
#define NCOLS   4096
#define KPAD    48               // 45 padded to 48 (3 k-tiles of 16 for 32x32x16)
#define NCHUNK  4
#define CHUNKC  (NCOLS / NCHUNK) // 1024 cols per chunk (one wave each)
#define CROUNDS (CHUNKC / 32)    // 32 col-rounds of 32 cols
#define LO_SCALE 4096.0f         // 2^12: keeps f16 residuals out of subnormal range
#define INV_LO   (1.0f / 4096.0f)

typedef _Float16 f16x8  __attribute__((ext_vector_type(8)));
typedef float    f32x16 __attribute__((ext_vector_type(16)));

// ws layout (~0.79 MB):
//   Bhi  : _Float16[4096 * 48]   ([col][k], pad zeroed)   0.39 MB
//   Blo  : _Float16[4096 * 48]   (residual * 2^12)        0.39 MB
// All loads in-range: no overread.

// ---------------------------------------------------------------------------
// Build B: split H (45 x 4096, [d][n]) into hi/lo f16 in [col][k] layout,
// 48 k's per col (96 B stride, 16B-aligned), pad k=45..47 zeroed.
__global__ void build_B_kernel(const float* __restrict__ H,
                               _Float16* __restrict__ Bhi,
                               _Float16* __restrict__ Blo) {
    const int n = blockIdx.x * 256 + threadIdx.x;
    _Float16 hi[KPAD], lo[KPAD];
    #pragma unroll
    for (int k = 0; k < 45; ++k) {
        const float h = H[k * NCOLS + n];
        const _Float16 h1 = (_Float16)h;
        hi[k] = h1;
        lo[k] = (_Float16)((h - (float)h1) * LO_SCALE);
    }
    #pragma unroll
    for (int k = 45; k < KPAD; ++k) { hi[k] = (_Float16)0.f; lo[k] = (_Float16)0.f; }
    f16x8* dh = (f16x8*)(Bhi + (size_t)n * KPAD);
    f16x8* dl = (f16x8*)(Blo + (size_t)n * KPAD);
    const f16x8* sh = (const f16x8*)hi;
    const f16x8* sl = (const f16x8*)lo;
    #pragma unroll
    for (int q = 0; q < KPAD / 8; ++q) { dh[q] = sh[q]; dl[q] = sl[q]; }
}

// ---------------------------------------------------------------------------
// Fused MFMA GEMM + argmax + chunk-reduce + LUT gather.
// Block = 512 threads = 8 waves = 4 chunks x 2 row-tiles (32 rows each).
// wave w: chunk = w&3 (1024 cols), rtile = w>>2 (rows rowblk + rtile*32 ..).
// Waves w and w+4 read the SAME B chunk -> L1 reuse.
//
// REGISTER BUDGET (measured rounds 2/3): 2nd launch_bounds arg behaves like
// CUDA min-blocks/CU: (512,4)->64-VGPR cap (spilled, 4.3GB traffic),
// (512,2)->128 cap (64-row waves spilled at exactly 128). This version's
// 32-row waves need ~112 VGPR: fits the 128 cap -> 4 waves/SIMD, no spill.
//
// 32x32 layouts: A[m=lane&31][k=(lane>>5)*8+j]; B[k=(lane>>5)*8+j][n=lane&31];
// C/D: col=lane&31, row=(reg&3)+8*(reg>>2)+4*(lane>>5)   (m74/m101-verified).
__global__ __launch_bounds__(512, 2) void score_argmax_kernel(
        const float* __restrict__ x,   // (1024, 480)
        const float* __restrict__ S,   // (30, 2, 15)
        const float* __restrict__ T,   // (30, 15)
        const _Float16* __restrict__ Bhi,
        const _Float16* __restrict__ Blo,
        const float* __restrict__ LUT, // (10, 4096, 2)
        float* __restrict__ out) {     // (81920, 2)
    const int tid  = threadIdx.x;
    const int lane = tid & 63;
    const int l31  = lane & 31;
    const int half = lane >> 5;                       // 0 or 1
    const int wid   = tid >> 6;                       // wave id [0,8)
    const int chunk = wid & 3;                        // B-chunk [0,4)
    const int rtile = wid >> 2;                       // row-tile [0,2)
    const int rowblk = blockIdx.x * 64;               // block's first row
    const int rowbase = rowblk + rtile * 32;          // wave's first row

    __shared__ float lds_best[NCHUNK][64];
    __shared__ int   lds_bidx[NCHUNK][64];

    // ---- inline A: afr[kt][j] = y(rowbase + l31, kt*16 + half*8 + j)
    // y = sign(x4·S - T - 1e-4), exactly ±1/0 in f16; zero for k >= 45.
    f16x8 afr[3];
    {
        const int row  = rowbase + l31;
        const int pair = row / 10;
        const int c2   = row - pair * 10;
        const int a    = pair >> 3;
        const int b    = pair & 7;
        const float* xp = x + a * 480 + b * 60;
        #pragma unroll
        for (int kt = 0; kt < 3; ++kt) {
            #pragma unroll
            for (int j = 0; j < 8; ++j) {
                const int k    = kt * 16 + half * 8 + j;     // [0,48)
                const bool pad = (k >= 45);
                const int kcl  = pad ? 0 : k;                // clamp for safe addrs
                const int cc   = kcl / 15;                   // const-divisor magic
                const int kk   = kcl - cc * 15;
                const int c    = c2 * 3 + cc;
                const float x0 = xp[c * 2 + 0];
                const float x1 = xp[c * 2 + 1];
                float v = x0 * S[(c * 2 + 0) * 15 + kk] + x1 * S[(c * 2 + 1) * 15 + kk];
                v = v - T[c * 15 + kk] - 1e-4f;
                const float yv = (v > 0.f) ? 1.f : ((v < 0.f) ? -1.f : 0.f);
                afr[kt][j] = pad ? (_Float16)0.f : (_Float16)yv;
            }
        }
    }

    float best[16];
    int   bidx[16];
    #pragma unroll
    for (int e = 0; e < 16; ++e) { best[e] = -INFINITY; bidx[e] = 0; }

    const int colbase0 = chunk * CHUNKC;
    // per-lane B base: col = colbase0 + l31, byte = col*96 + half*16 (+kt*32)
    const _Float16* hbase = Bhi + (size_t)(colbase0 + l31) * KPAD + half * 8;
    const _Float16* lbase = Blo + (size_t)(colbase0 + l31) * KPAD + half * 8;
    const size_t RS = (size_t)32 * KPAD;              // halves per 32-col round

    for (int ct = 0; ct < CROUNDS; ++ct) {
        // single-buffered B frags (hi/lo x 3 k-tiles); TLP (4 waves/SIMD,
        // L2-resident B) hides the load latency.
        f16x8 cb[6];
        {
            const _Float16* hp = hbase + (size_t)ct * RS;
            const _Float16* lp = lbase + (size_t)ct * RS;
            #pragma unroll
            for (int kt = 0; kt < 3; ++kt) {
                cb[kt]     = *(const f16x8*)(hp + kt * 16);
                cb[3 + kt] = *(const f16x8*)(lp + kt * 16);
            }
        }
        f32x16 ch = {0.f};
        f32x16 cl = {0.f};
        ch = __builtin_amdgcn_mfma_f32_32x32x16_f16(afr[0], cb[0], ch, 0, 0, 0);
        ch = __builtin_amdgcn_mfma_f32_32x32x16_f16(afr[1], cb[1], ch, 0, 0, 0);
        ch = __builtin_amdgcn_mfma_f32_32x32x16_f16(afr[2], cb[2], ch, 0, 0, 0);
        cl = __builtin_amdgcn_mfma_f32_32x32x16_f16(afr[0], cb[3], cl, 0, 0, 0);
        cl = __builtin_amdgcn_mfma_f32_32x32x16_f16(afr[1], cb[4], cl, 0, 0, 0);
        cl = __builtin_amdgcn_mfma_f32_32x32x16_f16(afr[2], cb[5], cl, 0, 0, 0);
        const int mycol = colbase0 + ct * 32 + l31;
        #pragma unroll
        for (int e = 0; e < 16; ++e) {
            const float s = fmaf(cl[e], INV_LO, ch[e]);
            if (s > best[e]) bidx[e] = mycol;   // cols ascend: > keeps first
            best[e] = fmaxf(best[e], s);
        }
    }

    // Cross-lane argmax over the 32 cols held by l31=0..31 (same half).
    // Tie -> smaller index (jnp.argmax first-index semantics).
    #pragma unroll
    for (int m = 1; m < 32; m <<= 1) {
        #pragma unroll
        for (int e = 0; e < 16; ++e) {
            const float ov = __shfl_xor(best[e], m, 64);
            const int   oi = __shfl_xor(bidx[e], m, 64);
            if (ov > best[e] || (ov == best[e] && oi < bidx[e])) {
                best[e] = ov; bidx[e] = oi;
            }
        }
    }

    if (l31 == 0) {   // lanes 0 and 32 write their half's rows
        #pragma unroll
        for (int e = 0; e < 16; ++e) {
            const int r64 = rtile * 32 + (e & 3) + 8 * (e >> 2) + 4 * half;
            lds_best[chunk][r64] = best[e];
            lds_bidx[chunk][r64] = bidx[e];
        }
    }
    __syncthreads();

    // Fold the 4 chunk partials (ascending chunk + strict > == global
    // first-index argmax), gather LUT, write out (row-major (1024,8,10,2)).
    if (tid < 64) {
        const int row = rowblk + tid;
        float bv = lds_best[0][tid];
        int   bi = lds_bidx[0][tid];
        #pragma unroll
        for (int c = 1; c < NCHUNK; ++c) {
            const float v = lds_best[c][tid];
            const int   i = lds_bidx[c][tid];
            if (v > bv) { bv = v; bi = i; }
        }
        const int pair = row / 10;
        const int c2   = row - pair * 10;
        const float* l = LUT + ((size_t)c2 * NCOLS + bi) * 2;
        out[row * 2 + 0] = l[0];
        out[row * 2 + 1] = l[1];
    }
}

// ---------------------------------------------------------------------------
extern "C" void kernel_launch(void* const* d_in, const int* in_sizes, int n_in,
                              void* d_out, int out_size, void* d_ws, size_t ws_size,
                              hipStream_t stream) {
    const float* x   = (const float*)d_in[0];  // 1024*480
    const float* S   = (const float*)d_in[1];  // 30*2*15
    const float* T   = (const float*)d_in[2];  // 30*15
    const float* H   = (const float*)d_in[3];  // 45*4096
    const float* LUT = (const float*)d_in[4];  // 10*4096*2
    float* out = (float*)d_out;                // 1024*8*10*2

    _Float16* Bhi = (_Float16*)d_ws;                          // 4096*48
    _Float16* Blo = Bhi + (size_t)NCOLS * KPAD;               // 4096*48

    build_B_kernel<<<16, 256, 0, stream>>>(H, Bhi, Blo);
    // 1280 blocks x 8 waves (4 chunks x 2 row-tiles of 32 rows) = 64 rows/block.
    // 10240 waves; ~112 VGPR under the 128 cap -> 4 waves/SIMD, 2.5 fills.
    score_argmax_kernel<<<1280, 512, 0, stream>>>(x, S, T, Bhi, Blo, LUT, out);
}

// Round 5
// 182.584 us; speedup vs baseline: 5.6265x; 1.2866x over previous
//
#include <hip/hip_runtime.h>
#include <math.h>

// Problem constants (N = 1024)
#define M_ROWS  81920            // 1024*8*10 score rows
#define NCOLS   4096
#define KPAD    48               // 45 padded to 48 (3 k-tiles of 16 for 32x32x16)
#define NCHUNK  4
#define CHUNKC  (NCOLS / NCHUNK) // 1024 cols per chunk (one wave each)
#define CROUNDS (CHUNKC / 32)    // 32 col-rounds of 32 cols
#define GHALVES 3072             // _Float16 per 32-col group: 6 bufs * 512
#define LO_SCALE 4096.0f         // 2^12: keeps f16 residuals out of subnormal range
#define INV_LO   (1.0f / 4096.0f)

typedef _Float16 f16x8  __attribute__((ext_vector_type(8)));
typedef float    f32x16 __attribute__((ext_vector_type(16)));

// ws layout (~0.79 MB):
//   Bfrag : _Float16[128 groups][6 bufs][512]   fragment-major, 0.79 MB
// Fragment-major: for 32-col group g, buffer f (f<3: hi k-tile f; f>=3: lo
// k-tile f-3), the 64 lanes' 16B MFMA B-fragments stored CONTIGUOUSLY at
// lane*16B. A wave's fragment load = one coalesced 1KB read (16 cache lines
// vs 48 for the old [col][k] layout -> 3x less L1 pipe occupancy, the
// measured round-4 bottleneck).

// ---------------------------------------------------------------------------
// Build Bfrag: split H (45 x 4096, [d][n]) into hi/lo f16, emit in
// fragment-major order. Lane mapping within a buffer: lane = half*32 + c,
// holding col (g*32+c), k's [kt*16 + half*8, +8), pad k=45..47 zeroed.
__global__ void build_B_kernel(const float* __restrict__ H,
                               _Float16* __restrict__ Bfrag) {
    const int n = blockIdx.x * 256 + threadIdx.x;     // col [0,4096)
    _Float16 hi[KPAD], lo[KPAD];
    #pragma unroll
    for (int k = 0; k < 45; ++k) {
        const float h = H[k * NCOLS + n];
        const _Float16 h1 = (_Float16)h;
        hi[k] = h1;
        lo[k] = (_Float16)((h - (float)h1) * LO_SCALE);
    }
    #pragma unroll
    for (int k = 45; k < KPAD; ++k) { hi[k] = (_Float16)0.f; lo[k] = (_Float16)0.f; }

    const int g = n >> 5;
    const int c = n & 31;
    _Float16* gbase = Bfrag + (size_t)g * GHALVES;
    #pragma unroll
    for (int f = 0; f < 6; ++f) {
        const int kt = (f < 3) ? f : f - 3;
        const _Float16* src = ((f < 3) ? hi : lo) + kt * 16;
        #pragma unroll
        for (int h = 0; h < 2; ++h) {
            // lane = h*32 + c  ->  halves offset lane*8
            *(f16x8*)(gbase + f * 512 + (h * 32 + c) * 8) =
                *(const f16x8*)(src + h * 8);
        }
    }
}

// ---------------------------------------------------------------------------
// Fused MFMA GEMM + argmax + chunk-reduce + LUT gather.
// Block = 512 threads = 8 waves = 4 chunks x 2 row-tiles (32 rows each).
// wave w: chunk = w&3 (1024 cols), rtile = w>>2. Waves w and w+4 read the
// SAME B chunk (L1 reuse).
//
// REGISTER BUDGET (measured r2/r3/r4): 2nd launch_bounds arg acts like CUDA
// min-blocks/CU: (512,4)->64-VGPR cap (spill), (512,2)->128 cap (fits: r4
// measured 48 arch VGPR + acc). Keep (512,2).
//
// 32x32 layouts: A[m=lane&31][k=(lane>>5)*8+j]; B[k=(lane>>5)*8+j][n=lane&31];
// C/D: col=lane&31, row=(reg&3)+8*(reg>>2)+4*(lane>>5)   (m74/m101-verified).
__global__ __launch_bounds__(512, 2) void score_argmax_kernel(
        const float* __restrict__ x,   // (1024, 480)
        const float* __restrict__ S,   // (30, 2, 15)
        const float* __restrict__ T,   // (30, 15)
        const _Float16* __restrict__ Bfrag,
        const float* __restrict__ LUT, // (10, 4096, 2)
        float* __restrict__ out) {     // (81920, 2)
    const int tid  = threadIdx.x;
    const int lane = tid & 63;
    const int l31  = lane & 31;
    const int half = lane >> 5;                       // 0 or 1
    const int wid   = tid >> 6;                       // wave id [0,8)
    const int chunk = wid & 3;                        // B-chunk [0,4)
    const int rtile = wid >> 2;                       // row-tile [0,2)
    const int rowblk = blockIdx.x * 64;               // block's first row
    const int rowbase = rowblk + rtile * 32;          // wave's first row

    __shared__ float lds_best[NCHUNK][64];
    __shared__ int   lds_bidx[NCHUNK][64];

    // ---- inline A: afr[kt][j] = y(rowbase + l31, kt*16 + half*8 + j)
    // y = sign(x4·S - T - 1e-4), exactly ±1/0 in f16; zero for k >= 45.
    f16x8 afr[3];
    {
        const int row  = rowbase + l31;
        const int pair = row / 10;
        const int c2   = row - pair * 10;
        const int a    = pair >> 3;
        const int b    = pair & 7;
        const float* xp = x + a * 480 + b * 60;
        #pragma unroll
        for (int kt = 0; kt < 3; ++kt) {
            #pragma unroll
            for (int j = 0; j < 8; ++j) {
                const int k    = kt * 16 + half * 8 + j;     // [0,48)
                const bool pad = (k >= 45);
                const int kcl  = pad ? 0 : k;                // clamp for safe addrs
                const int cc   = kcl / 15;                   // const-divisor magic
                const int kk   = kcl - cc * 15;
                const int c    = c2 * 3 + cc;
                const float x0 = xp[c * 2 + 0];
                const float x1 = xp[c * 2 + 1];
                float v = x0 * S[(c * 2 + 0) * 15 + kk] + x1 * S[(c * 2 + 1) * 15 + kk];
                v = v - T[c * 15 + kk] - 1e-4f;
                const float yv = (v > 0.f) ? 1.f : ((v < 0.f) ? -1.f : 0.f);
                afr[kt][j] = pad ? (_Float16)0.f : (_Float16)yv;
            }
        }
    }

    float best[16];
    int   bidx[16];
    #pragma unroll
    for (int e = 0; e < 16; ++e) { best[e] = -INFINITY; bidx[e] = 0; }

    const int colbase0 = chunk * CHUNKC;
    // fragment-major pointer: group (colbase0/32 + ct), lane's 16B at lane*16
    const _Float16* fptr = Bfrag + (size_t)(colbase0 >> 5) * GHALVES + (size_t)lane * 8;

    for (int ct = 0; ct < CROUNDS; ++ct) {
        // coalesced fragment loads: 6 x 1KB contiguous per wave
        f16x8 cb[6];
        #pragma unroll
        for (int f = 0; f < 6; ++f) cb[f] = *(const f16x8*)(fptr + f * 512);

        f32x16 ch = {0.f};
        f32x16 cl = {0.f};
        ch = __builtin_amdgcn_mfma_f32_32x32x16_f16(afr[0], cb[0], ch, 0, 0, 0);
        ch = __builtin_amdgcn_mfma_f32_32x32x16_f16(afr[1], cb[1], ch, 0, 0, 0);
        ch = __builtin_amdgcn_mfma_f32_32x32x16_f16(afr[2], cb[2], ch, 0, 0, 0);
        cl = __builtin_amdgcn_mfma_f32_32x32x16_f16(afr[0], cb[3], cl, 0, 0, 0);
        cl = __builtin_amdgcn_mfma_f32_32x32x16_f16(afr[1], cb[4], cl, 0, 0, 0);
        cl = __builtin_amdgcn_mfma_f32_32x32x16_f16(afr[2], cb[5], cl, 0, 0, 0);

        const int mycol = colbase0 + ct * 32 + l31;
        #pragma unroll
        for (int e = 0; e < 16; ++e) {
            const float s = fmaf(cl[e], INV_LO, ch[e]);
            if (s > best[e]) bidx[e] = mycol;   // cols ascend: > keeps first
            best[e] = fmaxf(best[e], s);
        }
        fptr += GHALVES;
    }

    // Cross-lane argmax over the 32 cols held by l31=0..31 (same half).
    // Tie -> smaller index (jnp.argmax first-index semantics).
    #pragma unroll
    for (int m = 1; m < 32; m <<= 1) {
        #pragma unroll
        for (int e = 0; e < 16; ++e) {
            const float ov = __shfl_xor(best[e], m, 64);
            const int   oi = __shfl_xor(bidx[e], m, 64);
            if (ov > best[e] || (ov == best[e] && oi < bidx[e])) {
                best[e] = ov; bidx[e] = oi;
            }
        }
    }

    if (l31 == 0) {   // lanes 0 and 32 write their half's rows
        #pragma unroll
        for (int e = 0; e < 16; ++e) {
            const int r64 = rtile * 32 + (e & 3) + 8 * (e >> 2) + 4 * half;
            lds_best[chunk][r64] = best[e];
            lds_bidx[chunk][r64] = bidx[e];
        }
    }
    __syncthreads();

    // Fold the 4 chunk partials (ascending chunk + strict > == global
    // first-index argmax), gather LUT, write out (row-major (1024,8,10,2)).
    if (tid < 64) {
        const int row = rowblk + tid;
        float bv = lds_best[0][tid];
        int   bi = lds_bidx[0][tid];
        #pragma unroll
        for (int c = 1; c < NCHUNK; ++c) {
            const float v = lds_best[c][tid];
            const int   i = lds_bidx[c][tid];
            if (v > bv) { bv = v; bi = i; }
        }
        const int pair = row / 10;
        const int c2   = row - pair * 10;
        const float* l = LUT + ((size_t)c2 * NCOLS + bi) * 2;
        out[row * 2 + 0] = l[0];
        out[row * 2 + 1] = l[1];
    }
}

// ---------------------------------------------------------------------------
extern "C" void kernel_launch(void* const* d_in, const int* in_sizes, int n_in,
                              void* d_out, int out_size, void* d_ws, size_t ws_size,
                              hipStream_t stream) {
    const float* x   = (const float*)d_in[0];  // 1024*480
    const float* S   = (const float*)d_in[1];  // 30*2*15
    const float* T   = (const float*)d_in[2];  // 30*15
    const float* H   = (const float*)d_in[3];  // 45*4096
    const float* LUT = (const float*)d_in[4];  // 10*4096*2
    float* out = (float*)d_out;                // 1024*8*10*2

    _Float16* Bfrag = (_Float16*)d_ws;         // 128 groups * 3072 halves

    build_B_kernel<<<16, 256, 0, stream>>>(H, Bfrag);
    // 1280 blocks x 8 waves (4 chunks x 2 row-tiles of 32 rows) = 64 rows/block.
    score_argmax_kernel<<<1280, 512, 0, stream>>>(x, S, T, Bfrag, LUT, out);
}